// Round 7
// baseline (384344.873 us; speedup 1.0000x reference)
//
#include <hip/hip_runtime.h>
#include <cstdint>
#include <cstddef>

// ---------------------------------------------------------------------------
// Tacotron2 decoder, MI355X. Round 7: persistent kernel with PLAIN launch +
// hand-rolled software grid barrier (hipLaunchCooperativeKernel proven to
// silently no-op under this harness: r5/r6 bit-identical failures = k_loop
// never executed). Phase structure identical to round 6; all phase bodies
// are round-2/4-verified code.
// grid 512 x 256, __launch_bounds__(256,2) => guide-blessed co-residency.
// ---------------------------------------------------------------------------

static constexpr int NSTEP = 250;
static constexpr unsigned GRID = 512;

// workspace offsets (floats). total = 17,430,528 floats (~69.7 MB)
static constexpr size_t OFF_ENCPROJ = 0;               // 819200
static constexpr size_t OFF_CWT     = 819200;          // 4096
static constexpr size_t OFF_KEYS    = 823296;          // 2048 (250*8 uints)
static constexpr size_t OFF_PRE2    = 825344;          // 2048000
static constexpr size_t OFF_G       = 2873344;         // 4096000
static constexpr size_t OFF_S2      = 6969344;         // 251*32768 = 8224768
static constexpr size_t OFF_S1      = 15194112;        // 65536 (ping-pong)
static constexpr size_t OFF_C1      = 15259648;        // 32768
static constexpr size_t OFF_C2      = 15292416;        // 32768
static constexpr size_t OFF_CUM     = 15325184;        // 6400 used
static constexpr size_t OFF_BAR     = 15331840;        // 2 uints (inside zeroed region)
static constexpr size_t OFF_P       = 15333376;        // 16*131072 (part overlaid)

// d_out offsets (floats)
static constexpr size_t OUT_TOK  = 1280000;
static constexpr size_t OUT_ATTN = 1296000;

// ---------------------------------------------------------------------------
// Threefry-2x32 (JAX partitionable split — verified bit-exact rounds 2/4)
// ---------------------------------------------------------------------------
__device__ __forceinline__ uint2 threefry(unsigned k0, unsigned k1, unsigned c0, unsigned c1) {
  unsigned ks2 = k0 ^ k1 ^ 0x1BD11BDAu;
  unsigned x0 = c0 + k0, x1 = c1 + k1;
#define TFR(rot) { x0 += x1; x1 = (x1 << (rot)) | (x1 >> (32 - (rot))); x1 ^= x0; }
  TFR(13) TFR(15) TFR(26) TFR(6)   x0 += k1;  x1 += ks2 + 1u;
  TFR(17) TFR(29) TFR(16) TFR(24)  x0 += ks2; x1 += k0 + 2u;
  TFR(13) TFR(15) TFR(26) TFR(6)   x0 += k0;  x1 += k1 + 3u;
  TFR(17) TFR(29) TFR(16) TFR(24)  x0 += k1;  x1 += ks2 + 4u;
  TFR(13) TFR(15) TFR(26) TFR(6)   x0 += ks2; x1 += k0 + 5u;
#undef TFR
  return make_uint2(x0, x1);
}

__device__ __forceinline__ float u32_to_uniform(unsigned b) {
  return __uint_as_float((b >> 9) | 0x3f800000u) - 1.0f;
}

__device__ __forceinline__ float rng_uniform(unsigned k0, unsigned k1, unsigned i) {
  uint2 h = threefry(k0, k1, 0u, i);
  return u32_to_uniform(h.x ^ h.y);
}

__device__ __forceinline__ float gatef(float x) { return tanhf(x * 0.5f) * 0.5f + 0.5f; }

#define FMA4(A, S, W) { (A).x = fmaf((S), (W).x, (A).x); (A).y = fmaf((S), (W).y, (A).y); \
                        (A).z = fmaf((S), (W).z, (A).z); (A).w = fmaf((S), (W).w, (A).w); }

// ---------------------------------------------------------------------------
// Software grid barrier (generation-counting, device-scope).
// ---------------------------------------------------------------------------
__device__ __forceinline__ void gbar(unsigned* cnt, unsigned* gen) {
  __syncthreads();
  if (threadIdx.x == 0) {
    __threadfence();   // release: make this block's writes visible device-wide
    unsigned my = __hip_atomic_load(gen, __ATOMIC_ACQUIRE, __HIP_MEMORY_SCOPE_AGENT);
    unsigned arrived = __hip_atomic_fetch_add(cnt, 1u, __ATOMIC_ACQ_REL, __HIP_MEMORY_SCOPE_AGENT);
    if (arrived == GRID - 1u) {
      __hip_atomic_store(cnt, 0u, __ATOMIC_RELEASE, __HIP_MEMORY_SCOPE_AGENT);
      __hip_atomic_fetch_add(gen, 1u, __ATOMIC_ACQ_REL, __HIP_MEMORY_SCOPE_AGENT);
    } else {
      while (__hip_atomic_load(gen, __ATOMIC_ACQUIRE, __HIP_MEMORY_SCOPE_AGENT) == my) {
        __builtin_amdgcn_s_sleep(2);
      }
    }
    __threadfence();   // acquire: see other blocks' writes
  }
  __syncthreads();
}

// ---------------------------------------------------------------------------
// k_init: zero state/cum/bar/attn-tail, RNG keys, fused conv weights CWt
// ---------------------------------------------------------------------------
__global__ __launch_bounds__(256) void k_init(float* __restrict__ ws, float* __restrict__ out,
                                              const float* __restrict__ conv_w,
                                              const float* __restrict__ Wcp) {
  const size_t NZERO1 = 139264;   // [OFF_S1, OFF_P): s1 x2, c1, c2, cum, bar
  const size_t NZERO2 = 32768;    // s2_all slot 0
  const size_t NATTN  = 1600000;  // attn rows 250..499
  const size_t NKEYS  = 250;
  const size_t NCWT   = 4096;
  const size_t TOTAL  = NZERO1 + NZERO2 + NATTN + NKEYS + NCWT;
  unsigned* keys = (unsigned*)(ws + OFF_KEYS);
  for (size_t i = (size_t)blockIdx.x * 256 + threadIdx.x; i < TOTAL; i += (size_t)gridDim.x * 256) {
    if (i < NZERO1) {
      ws[OFF_S1 + i] = 0.f;
    } else if (i < NZERO1 + NZERO2) {
      ws[OFF_S2 + (i - NZERO1)] = 0.f;
    } else if (i < NZERO1 + NZERO2 + NATTN) {
      size_t r = i - NZERO1 - NZERO2;
      size_t b = r / 50000, rem = r % 50000;
      out[OUT_ATTN + b * 100000 + 50000 + rem] = 0.f;
    } else if (i < NZERO1 + NZERO2 + NATTN + NKEYS) {
      int s = (int)(i - NZERO1 - NZERO2 - NATTN);
      uint2 F = threefry(0u, 1234u, 0u, (unsigned)s);
      uint2 kd1 = threefry(F.x, F.y, 0u, 0u);
      uint2 kd2 = threefry(F.x, F.y, 0u, 1u);
      uint2 kz1 = threefry(F.x, F.y, 0u, 2u);
      uint2 kz2 = threefry(F.x, F.y, 0u, 3u);
      keys[s * 8 + 0] = kd1.x; keys[s * 8 + 1] = kd1.y;
      keys[s * 8 + 2] = kd2.x; keys[s * 8 + 3] = kd2.y;
      keys[s * 8 + 4] = kz1.x; keys[s * 8 + 5] = kz1.y;
      keys[s * 8 + 6] = kz2.x; keys[s * 8 + 7] = kz2.y;
    } else {
      size_t r = i - NZERO1 - NZERO2 - NATTN - NKEYS;   // [0,4096)
      int a = (int)(r >> 5), kk = (int)(r & 31);
      float v = 0.f;
      if (kk < 31) {
        for (int f = 0; f < 32; ++f) v = fmaf(conv_w[f * 31 + kk], Wcp[f * 128 + a], v);
      }
      ws[OFF_CWT + r] = v;   // CWt[a][k], row stride 32
    }
  }
}

// ---------------------------------------------------------------------------
// k_encproj: encproj = e_outputs @ W_encproj + b  ([6400,512]@[512,128])
// ---------------------------------------------------------------------------
__global__ __launch_bounds__(256) void k_encproj(const float* __restrict__ e_out,
                                                 const float* __restrict__ Wenc,
                                                 const float* __restrict__ benc,
                                                 float* __restrict__ encproj) {
  __shared__ __align__(16) float xs[32 * 516];
  int t = threadIdx.x;
  int r0 = blockIdx.x * 32;
  for (int i = 0; i < 64; ++i) {
    int idx = t + 256 * i; int rb = idx >> 9, kk = idx & 511;
    xs[rb * 516 + kk] = e_out[(size_t)(r0 + rb) * 512 + kk];
  }
  __syncthreads();
  int a = t & 127, rh = t >> 7;
  float acc[16];
#pragma unroll
  for (int r = 0; r < 16; ++r) acc[r] = 0.f;
  const float4* xv = (const float4*)xs;
  for (int k4 = 0; k4 < 128; ++k4) {
    const float* wp = Wenc + (size_t)(k4 * 4) * 128 + a;
    float w0 = wp[0], w1 = wp[128], w2 = wp[256], w3 = wp[384];
#pragma unroll
    for (int r = 0; r < 16; ++r) {
      float4 x4 = xv[(rh * 16 + r) * 129 + k4];
      acc[r] = fmaf(x4.x, w0, acc[r]); acc[r] = fmaf(x4.y, w1, acc[r]);
      acc[r] = fmaf(x4.z, w2, acc[r]); acc[r] = fmaf(x4.w, w3, acc[r]);
    }
  }
  float bb = benc[a];
  for (int r = 0; r < 16; ++r)
    encproj[(size_t)(r0 + rh * 16 + r) * 128 + a] = acc[r] + bb;
}

// ---------------------------------------------------------------------------
// k_prenet: all 250 steps, exact dropout
// ---------------------------------------------------------------------------
__global__ __launch_bounds__(256) void k_prenet(const float* __restrict__ mel,
                                                const float* __restrict__ W1, const float* __restrict__ b1,
                                                const float* __restrict__ W2, const float* __restrict__ b2,
                                                const unsigned* __restrict__ keys,
                                                float* __restrict__ pre2_all) {
  int s = blockIdx.x, t = threadIdx.x;
  __shared__ __align__(16) float prev[32 * 80];
  __shared__ __align__(16) float p1[32 * 256];
  for (int i = 0; i < 10; ++i) {
    int idx = t + 256 * i;
    int bb = idx / 80, vv = idx % 80;
    prev[idx] = (s == 0) ? 0.f : mel[(size_t)bb * 40000 + (size_t)(2 * s - 1) * 80 + vv];
  }
  __syncthreads();
  unsigned kd10 = keys[s * 8 + 0], kd11 = keys[s * 8 + 1];
  unsigned kd20 = keys[s * 8 + 2], kd21 = keys[s * 8 + 3];
  float acc[32];
  float bias = b1[t];
#pragma unroll
  for (int b = 0; b < 32; ++b) acc[b] = bias;
  for (int k4 = 0; k4 < 20; ++k4) {
    const float* wp = W1 + (size_t)(k4 * 4) * 256 + t;
    float w0 = wp[0], w1 = wp[256], w2 = wp[512], w3 = wp[768];
#pragma unroll
    for (int b = 0; b < 32; ++b) {
      float4 x4 = *(const float4*)(prev + b * 80 + k4 * 4);
      acc[b] = fmaf(x4.x, w0, acc[b]); acc[b] = fmaf(x4.y, w1, acc[b]);
      acc[b] = fmaf(x4.z, w2, acc[b]); acc[b] = fmaf(x4.w, w3, acc[b]);
    }
  }
#pragma unroll
  for (int b = 0; b < 32; ++b) {
    float r = fmaxf(acc[b], 0.f);
    float u = rng_uniform(kd10, kd11, (unsigned)(b * 256 + t));
    p1[b * 256 + t] = (u < 0.5f) ? r * 2.f : 0.f;
  }
  __syncthreads();
  float bias2 = b2[t];
#pragma unroll
  for (int b = 0; b < 32; ++b) acc[b] = bias2;
  for (int k4 = 0; k4 < 64; ++k4) {
    const float* wp = W2 + (size_t)(k4 * 4) * 256 + t;
    float w0 = wp[0], w1 = wp[256], w2 = wp[512], w3 = wp[768];
#pragma unroll
    for (int b = 0; b < 32; ++b) {
      float4 x4 = *(const float4*)(p1 + b * 256 + k4 * 4);
      acc[b] = fmaf(x4.x, w0, acc[b]); acc[b] = fmaf(x4.y, w1, acc[b]);
      acc[b] = fmaf(x4.z, w2, acc[b]); acc[b] = fmaf(x4.w, w3, acc[b]);
    }
  }
  for (int b = 0; b < 32; ++b) {
    float r = fmaxf(acc[b], 0.f);
    float u = rng_uniform(kd20, kd21, (unsigned)(b * 256 + t));
    pre2_all[(size_t)(s * 32 + b) * 256 + t] = (u < 0.5f) ? r * 2.f : 0.f;
  }
}

// ---------------------------------------------------------------------------
// k_loop: persistent kernel, plain launch. grid 512 x 256, 5 gbar()/step.
// ---------------------------------------------------------------------------
struct KP {
  const float* e_out;
  const float* Wdec; const float* Wself;
  const float* Wys; const float* Wss; const float* Wgs; const float* bgs;
  const float* Wis; const float* Wss2; const float* bss2;
  float* ws; float* out;
};

__global__ __launch_bounds__(256, 2) void k_loop(KP p) {
  __shared__ __align__(16) float smem[32 * 132];   // 4224 floats
  const int blk = blockIdx.x, t = threadIdx.x;
  float* ws = p.ws;
  const float* encproj = ws + OFF_ENCPROJ;
  const float* cwt = ws + OFF_CWT;
  const unsigned* keys = (const unsigned*)(ws + OFF_KEYS);
  const float* pre2_all = ws + OFF_PRE2;
  float* g_all = ws + OFF_G;
  float* s2_all = ws + OFF_S2;
  float* s1buf = ws + OFF_S1;
  float* c1 = ws + OFF_C1;
  float* c2 = ws + OFF_C2;
  float* cum = ws + OFF_CUM;
  unsigned* bar = (unsigned*)(ws + OFF_BAR);
  unsigned* bcnt = bar; unsigned* bgen = bar + 1;
  float* part = ws + OFF_P;

  for (int s = 0; s < NSTEP; ++s) {
    float* s1old = s1buf + (size_t)(s & 1) * 32768;
    float* s1new = s1buf + (size_t)((s + 1) & 1) * 32768;
    float* s2s = s2_all + (size_t)s * 32768;
    float* s2n = s2_all + (size_t)(s + 1) * 32768;
    float* gs = g_all + (size_t)s * 16384;

    // ==== PhA: full attention, one block per b (round-2-verified body) ====
    if (blk < 32) {
      int b = blk;
      float* dpp = smem;          // 256
      float* dpf = smem + 256;    // 128
      float* ca  = smem + 384;    // 232
      float* sc  = smem + 616;    // 200
      float* red = smem + 816;    // 8
      float* bcv = smem + 824;    // 2
      if (t < 232) ca[t] = (t >= 15 && t < 215) ? cum[b * 200 + (t - 15)] : 0.f;
      if (t < 200) sc[t] = 0.f;
      int a = t & 127, h = t >> 7;
      {
        const float* s2b = s2s + b * 1024 + h * 512;
        const float* wd = p.Wdec + (size_t)(h * 512) * 128 + a;
        float acc = 0.f;
        for (int d4 = 0; d4 < 128; ++d4) {
          float4 s4 = *(const float4*)(s2b + d4 * 4);
          acc = fmaf(s4.x, wd[(d4 * 4 + 0) * 128], acc);
          acc = fmaf(s4.y, wd[(d4 * 4 + 1) * 128], acc);
          acc = fmaf(s4.z, wd[(d4 * 4 + 2) * 128], acc);
          acc = fmaf(s4.w, wd[(d4 * 4 + 3) * 128], acc);
        }
        dpp[t] = acc;
      }
      __syncthreads();
      if (t < 128) dpf[t] = dpp[t] + dpp[t + 128];
      __syncthreads();
      float cwr[31];
#pragma unroll
      for (int k = 0; k < 31; ++k) cwr[k] = cwt[a * 32 + k];
      float wself_r = p.Wself[a];
      float dp_r = dpf[a];
      const float* epb = encproj + (size_t)(b * 200) * 128 + a;
      for (int ii = 0; ii < 25; ++ii) {
        int l0 = h + 8 * ii;
        float car[37];
#pragma unroll
        for (int m = 0; m < 37; ++m) car[m] = ca[l0 + m];
#pragma unroll
        for (int j = 0; j < 4; ++j) {
          int l = l0 + 2 * j;
          float conv = 0.f;
#pragma unroll
          for (int k = 0; k < 31; ++k) conv = fmaf(car[2 * j + k], cwr[k], conv);
          float e = tanhf(dp_r + epb[(size_t)l * 128] + conv);
          float v = e * wself_r;
#pragma unroll
          for (int off = 32; off > 0; off >>= 1) v += __shfl_xor(v, off, 64);
          if ((t & 63) == 0) atomicAdd(&sc[l], v);
        }
      }
      __syncthreads();
      float v = (t < 200) ? sc[t] : -3.4e38f;
#pragma unroll
      for (int off = 32; off > 0; off >>= 1) v = fmaxf(v, __shfl_xor(v, off, 64));
      if ((t & 63) == 0) red[t >> 6] = v;
      __syncthreads();
      if (t == 0) bcv[0] = fmaxf(fmaxf(red[0], red[1]), fmaxf(red[2], red[3]));
      __syncthreads();
      float mx = bcv[0];
      float ex = (t < 200) ? expf(sc[t] - mx) : 0.f;
      float sv = ex;
#pragma unroll
      for (int off = 32; off > 0; off >>= 1) sv += __shfl_xor(sv, off, 64);
      if ((t & 63) == 0) red[4 + (t >> 6)] = sv;
      __syncthreads();
      if (t == 0) bcv[1] = (red[4] + red[5]) + (red[6] + red[7]);
      __syncthreads();
      float denom = bcv[1];
      if (t < 200) {
        float al = ex / denom;
        sc[t] = al;
        cum[b * 200 + t] += al;
        p.out[OUT_ATTN + (size_t)s * 200 + (size_t)b * 100000 + t] = al;
      }
      __syncthreads();
      const float* eb = p.e_out + (size_t)b * 102400;
#pragma unroll 1
      for (int rep = 0; rep < 2; ++rep) {
        int d = t + 256 * rep;
        float acc = 0.f;
#pragma unroll 4
        for (int l = 0; l < 200; ++l) acc = fmaf(sc[l], eb[(size_t)l * 512 + d], acc);
        gs[b * 512 + d] = acc;
      }
    }
    gbar(bcnt, bgen);

    // ==== PhB: LSTM1 GEMM partials (448 of 512 blocks, K=128 x 14 chunks) ====
    {
      int jt = blk & 31, c = blk >> 5;   // c 0..15, active c<14
      if (c < 14) {
        float* xs = smem;
        {
          int r = t >> 3, kq = t & 7;
          const float* src;
          if (c < 2)       src = pre2_all + (size_t)s * 8192 + r * 256 + c * 128;
          else if (c < 10) src = s1old + r * 1024 + (c - 2) * 128;
          else             src = gs + r * 512 + (c - 10) * 128;
          const float4* s4 = (const float4*)(src + kq * 16);
          float4* d4 = (float4*)(xs + r * 132 + kq * 16);
          d4[0] = s4[0]; d4[1] = s4[1]; d4[2] = s4[2]; d4[3] = s4[3];
        }
        const float* W0; int k0;
        if (c < 2)       { W0 = p.Wys; k0 = c * 128; }
        else if (c < 10) { W0 = p.Wss; k0 = (c - 2) * 128; }
        else             { W0 = p.Wgs; k0 = (c - 10) * 128; }
        __syncthreads();
        int jq = t & 31, bq = t >> 5, j = jt * 32 + jq;
        float4 acc[4];
        acc[0] = acc[1] = acc[2] = acc[3] = make_float4(0, 0, 0, 0);
        const float4* xv = (const float4*)xs;
        const float* Wb = W0 + (size_t)k0 * 4096 + j;
#pragma unroll 4
        for (int k4 = 0; k4 < 32; ++k4) {
          float4 xq[4];
          xq[0] = xv[(bq * 4 + 0) * 33 + k4];
          xq[1] = xv[(bq * 4 + 1) * 33 + k4];
          xq[2] = xv[(bq * 4 + 2) * 33 + k4];
          xq[3] = xv[(bq * 4 + 3) * 33 + k4];
          const float* wr = Wb + (size_t)(k4 * 4) * 4096;
#pragma unroll
          for (int ks = 0; ks < 4; ++ks) {
            float wi = wr[0], wf = wr[1024], wc = wr[2048], wo = wr[3072];
            wr += 4096;
#pragma unroll
            for (int r = 0; r < 4; ++r) {
              float xval = ((const float*)&xq[r])[ks];
              acc[r].x = fmaf(xval, wi, acc[r].x);
              acc[r].y = fmaf(xval, wf, acc[r].y);
              acc[r].z = fmaf(xval, wc, acc[r].z);
              acc[r].w = fmaf(xval, wo, acc[r].w);
            }
          }
        }
        float* pb = part + (size_t)c * 131072 + (size_t)(bq * 4) * 4096 + j;
#pragma unroll
        for (int r = 0; r < 4; ++r) {
          float* pr = pb + r * 4096;
          pr[0] = acc[r].x; pr[1024] = acc[r].y; pr[2048] = acc[r].z; pr[3072] = acc[r].w;
        }
      }
    }
    gbar(bcnt, bgen);

    // ==== PhC: cell1 (blocks 0..127) ====
    if (blk < 128) {
      int e = blk * 256 + t;
      int j = e & 1023, b = e >> 10;
      float gi = p.bgs[j], gf = p.bgs[1024 + j], gc = p.bgs[2048 + j], go = p.bgs[3072 + j];
      const float* pc = part + (size_t)b * 4096 + j;
      for (int cc = 0; cc < 14; ++cc) {
        const float* p2 = pc + (size_t)cc * 131072;
        gi += p2[0]; gf += p2[1024]; gc += p2[2048]; go += p2[3072];
      }
      float u = rng_uniform(keys[s * 8 + 4], keys[s * 8 + 5], (unsigned)e);
      float m = floorf(u + 0.1f);
      float co = c1[e], so = s1old[e];
      float cn = fmaf(gatef(gf), co, gatef(gi) * tanhf(gc));
      float cnew = (m > 0.5f) ? co : cn;
      float sn = gatef(go) * tanhf(cnew);
      c1[e] = cnew;
      s1new[e] = (m > 0.5f) ? so : sn;
    }
    gbar(bcnt, bgen);

    // ==== PhD: LSTM2 GEMM partials (512 blocks, K=128 x 16 chunks) ====
    {
      int jt = blk & 31, c = blk >> 5;   // 0..15
      float* xs = smem;
      {
        int r = t >> 3, kq = t & 7;
        const float* src = (c < 8) ? (s1new + r * 1024 + c * 128)
                                   : (s2s + r * 1024 + (c - 8) * 128);
        const float4* s4 = (const float4*)(src + kq * 16);
        float4* d4 = (float4*)(xs + r * 132 + kq * 16);
        d4[0] = s4[0]; d4[1] = s4[1]; d4[2] = s4[2]; d4[3] = s4[3];
      }
      const float* W0 = (c < 8) ? p.Wis : p.Wss2;
      int k0 = (c & 7) * 128;
      __syncthreads();
      int jq = t & 31, bq = t >> 5, j = jt * 32 + jq;
      float4 acc[4];
      acc[0] = acc[1] = acc[2] = acc[3] = make_float4(0, 0, 0, 0);
      const float4* xv = (const float4*)xs;
      const float* Wb = W0 + (size_t)k0 * 4096 + j;
#pragma unroll 4
      for (int k4 = 0; k4 < 32; ++k4) {
        float4 xq[4];
        xq[0] = xv[(bq * 4 + 0) * 33 + k4];
        xq[1] = xv[(bq * 4 + 1) * 33 + k4];
        xq[2] = xv[(bq * 4 + 2) * 33 + k4];
        xq[3] = xv[(bq * 4 + 3) * 33 + k4];
        const float* wr = Wb + (size_t)(k4 * 4) * 4096;
#pragma unroll
        for (int ks = 0; ks < 4; ++ks) {
          float wi = wr[0], wf = wr[1024], wc = wr[2048], wo = wr[3072];
          wr += 4096;
#pragma unroll
          for (int r = 0; r < 4; ++r) {
            float xval = ((const float*)&xq[r])[ks];
            acc[r].x = fmaf(xval, wi, acc[r].x);
            acc[r].y = fmaf(xval, wf, acc[r].y);
            acc[r].z = fmaf(xval, wc, acc[r].z);
            acc[r].w = fmaf(xval, wo, acc[r].w);
          }
        }
      }
      float* pb = part + (size_t)c * 131072 + (size_t)(bq * 4) * 4096 + j;
#pragma unroll
      for (int r = 0; r < 4; ++r) {
        float* pr = pb + r * 4096;
        pr[0] = acc[r].x; pr[1024] = acc[r].y; pr[2048] = acc[r].z; pr[3072] = acc[r].w;
      }
    }
    gbar(bcnt, bgen);

    // ==== PhE: cell2 (blocks 0..127) ====
    if (blk < 128) {
      int e = blk * 256 + t;
      int j = e & 1023, b = e >> 10;
      float gi = p.bss2[j], gf = p.bss2[1024 + j], gc = p.bss2[2048 + j], go = p.bss2[3072 + j];
      const float* pc = part + (size_t)b * 4096 + j;
      for (int cc = 0; cc < 16; ++cc) {
        const float* p2 = pc + (size_t)cc * 131072;
        gi += p2[0]; gf += p2[1024]; gc += p2[2048]; go += p2[3072];
      }
      float u = rng_uniform(keys[s * 8 + 6], keys[s * 8 + 7], (unsigned)e);
      float m = floorf(u + 0.1f);
      float co = c2[e], so = s2s[e];
      float cn = fmaf(gatef(gf), co, gatef(gi) * tanhf(gc));
      float cnew = (m > 0.5f) ? co : cn;
      float sn = gatef(go) * tanhf(cnew);
      c2[e] = cnew;
      s2n[e] = (m > 0.5f) ? so : sn;
    }
    gbar(bcnt, bgen);
  }
}

// ---------------------------------------------------------------------------
// k_frame: deferred frame/token projection. grid 250.
// ---------------------------------------------------------------------------
__global__ __launch_bounds__(256) void k_frame(const float* __restrict__ s2_all,
                                               const float* __restrict__ g_all,
                                               const float* __restrict__ Wf,
                                               const float* __restrict__ bf,
                                               const float* __restrict__ Wt,
                                               const float* __restrict__ bt,
                                               float* __restrict__ out_frame,
                                               float* __restrict__ out_tok) {
  int s = blockIdx.x, t = threadIdx.x;
  __shared__ __align__(16) float xs[32 * 516];
  int b = t >> 3, ci = t & 7;
  int tb = t >> 1, tr = t & 1;
  float4 acc[5];
#pragma unroll
  for (int r = 0; r < 5; ++r) acc[r] = make_float4(0, 0, 0, 0);
  float tok = 0.f;
  for (int ch = 0; ch < 3; ++ch) {
    for (int i = 0; i < 64; ++i) {
      int idx = t + 256 * i;
      int rb = idx >> 9, kk = idx & 511;
      float vsrc = (ch < 2) ? s2_all[(size_t)(s + 1) * 32768 + rb * 1024 + ch * 512 + kk]
                            : g_all[(size_t)s * 16384 + rb * 512 + kk];
      xs[rb * 516 + kk] = vsrc;
    }
    __syncthreads();
    const float4* xv = (const float4*)xs;
    for (int k4 = 0; k4 < 128; ++k4) {
      float4 x4 = xv[b * 129 + k4];
      int kglob = ch * 512 + k4 * 4;
#pragma unroll
      for (int rep = 0; rep < 5; ++rep) {
        int c4 = ci * 4 + rep * 32;
        const float* wrow = Wf + (size_t)kglob * 160 + c4;
        float4 w0 = *(const float4*)(wrow);
        float4 w1 = *(const float4*)(wrow + 160);
        float4 w2 = *(const float4*)(wrow + 320);
        float4 w3 = *(const float4*)(wrow + 480);
        FMA4(acc[rep], x4.x, w0); FMA4(acc[rep], x4.y, w1);
        FMA4(acc[rep], x4.z, w2); FMA4(acc[rep], x4.w, w3);
      }
      if (t < 64) {
        float4 xt = xv[tb * 129 + k4];
        tok = fmaf(xt.x, Wt[(size_t)(kglob + 0) * 2 + tr], tok);
        tok = fmaf(xt.y, Wt[(size_t)(kglob + 1) * 2 + tr], tok);
        tok = fmaf(xt.z, Wt[(size_t)(kglob + 2) * 2 + tr], tok);
        tok = fmaf(xt.w, Wt[(size_t)(kglob + 3) * 2 + tr], tok);
      }
    }
    __syncthreads();
  }
#pragma unroll
  for (int rep = 0; rep < 5; ++rep) {
    float vals[4] = {acc[rep].x, acc[rep].y, acc[rep].z, acc[rep].w};
#pragma unroll
    for (int jj = 0; jj < 4; ++jj) {
      int cc = ci * 4 + rep * 32 + jj;
      float val = vals[jj] + bf[cc];
      int row = 2 * s + (cc >= 80 ? 1 : 0);
      int col = cc - (cc >= 80 ? 80 : 0);
      out_frame[(size_t)b * 40000 + (size_t)row * 80 + col] = val;
    }
  }
  if (t < 64) out_tok[(size_t)tb * 500 + 2 * s + tr] = tok + bt[tr];
}

// ---------------------------------------------------------------------------
extern "C" void kernel_launch(void* const* d_in, const int* in_sizes, int n_in,
                              void* d_out_v, int out_size, void* d_ws, size_t ws_size,
                              hipStream_t stream) {
  (void)in_sizes; (void)n_in; (void)out_size; (void)ws_size;
  const float* mel      = (const float*)d_in[0];
  const float* e_out    = (const float*)d_in[1];
  const float* conv_w   = (const float*)d_in[2];
  const float* Wcp      = (const float*)d_in[3];
  const float* Wenc     = (const float*)d_in[4];
  const float* benc     = (const float*)d_in[5];
  const float* Wdec     = (const float*)d_in[6];
  const float* Wself    = (const float*)d_in[7];
  const float* Wp1      = (const float*)d_in[8];
  const float* bp1      = (const float*)d_in[9];
  const float* Wp2      = (const float*)d_in[10];
  const float* bp2      = (const float*)d_in[11];
  const float* Wys      = (const float*)d_in[12];
  const float* Wss      = (const float*)d_in[13];
  const float* Wgs      = (const float*)d_in[14];
  const float* bgs      = (const float*)d_in[15];
  const float* Wis      = (const float*)d_in[16];
  const float* Wss2     = (const float*)d_in[17];
  const float* bss2     = (const float*)d_in[18];
  const float* Wf       = (const float*)d_in[19];
  const float* bf       = (const float*)d_in[20];
  const float* Wt       = (const float*)d_in[21];
  const float* bt       = (const float*)d_in[22];
  float* ws  = (float*)d_ws;
  float* out = (float*)d_out_v;
  const unsigned* keys = (const unsigned*)(ws + OFF_KEYS);

  hipLaunchKernelGGL(k_init, dim3(1024), dim3(256), 0, stream, ws, out, conv_w, Wcp);
  hipLaunchKernelGGL(k_encproj, dim3(200), dim3(256), 0, stream, e_out, Wenc, benc, ws + OFF_ENCPROJ);
  hipLaunchKernelGGL(k_prenet, dim3(250), dim3(256), 0, stream, mel, Wp1, bp1, Wp2, bp2, keys, ws + OFF_PRE2);

  KP kp;
  kp.e_out = e_out; kp.Wdec = Wdec; kp.Wself = Wself;
  kp.Wys = Wys; kp.Wss = Wss; kp.Wgs = Wgs; kp.bgs = bgs;
  kp.Wis = Wis; kp.Wss2 = Wss2; kp.bss2 = bss2;
  kp.ws = ws; kp.out = out;
  hipLaunchKernelGGL(k_loop, dim3(GRID), dim3(256), 0, stream, kp);

  hipLaunchKernelGGL(k_frame, dim3(250), dim3(256), 0, stream,
                     ws + OFF_S2, ws + OFF_G, Wf, bf, Wt, bt, out, out + OUT_TOK);
}

// Round 8
// 335385.278 us; speedup vs baseline: 1.1460x; 1.1460x over previous
//
#include <hip/hip_runtime.h>
#include <cstdint>
#include <cstddef>

// ---------------------------------------------------------------------------
// Tacotron2 decoder, MI355X. Round 8: identical to round 7 (PASSING, 384ms)
// except the grid barrier: flag-array + single-aggregator-block instead of
// one atomicAdd line (512 serialized cross-XCD RMWs = ~300us/barrier was the
// entire regression; VALUBusy 0.85%). Stores to distinct lines + read-only
// polling parallelize; release/acquire chain via block 0 preserves the
// transitive happens-before the r7 barrier provided.
// ---------------------------------------------------------------------------

static constexpr int NSTEP = 250;
static constexpr unsigned GRID = 512;

// workspace offsets (floats). total = 17,430,528 floats (~69.7 MB)
static constexpr size_t OFF_ENCPROJ = 0;               // 819200
static constexpr size_t OFF_CWT     = 819200;          // 4096
static constexpr size_t OFF_KEYS    = 823296;          // 2048 (250*8 uints)
static constexpr size_t OFF_PRE2    = 825344;          // 2048000
static constexpr size_t OFF_G       = 2873344;         // 4096000
static constexpr size_t OFF_S2      = 6969344;         // 251*32768 = 8224768
static constexpr size_t OFF_S1      = 15194112;        // 65536 (ping-pong)
static constexpr size_t OFF_C1      = 15259648;        // 32768
static constexpr size_t OFF_C2      = 15292416;        // 32768
static constexpr size_t OFF_CUM     = 15325184;        // 6400 used
static constexpr size_t OFF_BAR     = 15331584;        // 513 uints: flags[512], gen
static constexpr size_t OFF_P       = 15333376;        // 16*131072 (part overlaid)

// d_out offsets (floats)
static constexpr size_t OUT_TOK  = 1280000;
static constexpr size_t OUT_ATTN = 1296000;

// ---------------------------------------------------------------------------
// Threefry-2x32 (JAX partitionable split — verified bit-exact rounds 2/4/7)
// ---------------------------------------------------------------------------
__device__ __forceinline__ uint2 threefry(unsigned k0, unsigned k1, unsigned c0, unsigned c1) {
  unsigned ks2 = k0 ^ k1 ^ 0x1BD11BDAu;
  unsigned x0 = c0 + k0, x1 = c1 + k1;
#define TFR(rot) { x0 += x1; x1 = (x1 << (rot)) | (x1 >> (32 - (rot))); x1 ^= x0; }
  TFR(13) TFR(15) TFR(26) TFR(6)   x0 += k1;  x1 += ks2 + 1u;
  TFR(17) TFR(29) TFR(16) TFR(24)  x0 += ks2; x1 += k0 + 2u;
  TFR(13) TFR(15) TFR(26) TFR(6)   x0 += k0;  x1 += k1 + 3u;
  TFR(17) TFR(29) TFR(16) TFR(24)  x0 += k1;  x1 += ks2 + 4u;
  TFR(13) TFR(15) TFR(26) TFR(6)   x0 += ks2; x1 += k0 + 5u;
#undef TFR
  return make_uint2(x0, x1);
}

__device__ __forceinline__ float u32_to_uniform(unsigned b) {
  return __uint_as_float((b >> 9) | 0x3f800000u) - 1.0f;
}

__device__ __forceinline__ float rng_uniform(unsigned k0, unsigned k1, unsigned i) {
  uint2 h = threefry(k0, k1, 0u, i);
  return u32_to_uniform(h.x ^ h.y);
}

__device__ __forceinline__ float gatef(float x) { return tanhf(x * 0.5f) * 0.5f + 0.5f; }

#define FMA4(A, S, W) { (A).x = fmaf((S), (W).x, (A).x); (A).y = fmaf((S), (W).y, (A).y); \
                        (A).z = fmaf((S), (W).z, (A).z); (A).w = fmaf((S), (W).w, (A).w); }

// ---------------------------------------------------------------------------
// Flag-array grid barrier. flags[512] + gen, all monotonically increasing.
// Block i (i>0): release-store flags[i]=g; poll gen >= g.
// Block 0: 256 threads poll flags[1..511] >= g in parallel; release-store gen=g.
// No RMW contention; reads are parallel. HB chain: i -> 0 -> j (transitive).
// ---------------------------------------------------------------------------
__device__ __forceinline__ void gbar(unsigned* flags, unsigned* gen, unsigned g) {
  __syncthreads();
  if (blockIdx.x == 0) {
    int t = threadIdx.x;
#pragma unroll
    for (int rep = 0; rep < 2; ++rep) {
      int f = t + rep * 256;
      if (f > 0) {
        while (__hip_atomic_load(&flags[f], __ATOMIC_ACQUIRE, __HIP_MEMORY_SCOPE_AGENT) < g) {
          __builtin_amdgcn_s_sleep(1);
        }
      }
    }
    __syncthreads();
    if (t == 0) __hip_atomic_store(gen, g, __ATOMIC_RELEASE, __HIP_MEMORY_SCOPE_AGENT);
  } else {
    if (threadIdx.x == 0) {
      __hip_atomic_store(&flags[blockIdx.x], g, __ATOMIC_RELEASE, __HIP_MEMORY_SCOPE_AGENT);
      while (__hip_atomic_load(gen, __ATOMIC_ACQUIRE, __HIP_MEMORY_SCOPE_AGENT) < g) {
        __builtin_amdgcn_s_sleep(4);
      }
    }
  }
  __syncthreads();
}

// ---------------------------------------------------------------------------
// k_init: zero state/cum/bar/attn-tail, RNG keys, fused conv weights CWt
// ---------------------------------------------------------------------------
__global__ __launch_bounds__(256) void k_init(float* __restrict__ ws, float* __restrict__ out,
                                              const float* __restrict__ conv_w,
                                              const float* __restrict__ Wcp) {
  const size_t NZERO1 = 139264;   // [OFF_S1, OFF_P): s1 x2, c1, c2, cum, bar
  const size_t NZERO2 = 32768;    // s2_all slot 0
  const size_t NATTN  = 1600000;  // attn rows 250..499
  const size_t NKEYS  = 250;
  const size_t NCWT   = 4096;
  const size_t TOTAL  = NZERO1 + NZERO2 + NATTN + NKEYS + NCWT;
  unsigned* keys = (unsigned*)(ws + OFF_KEYS);
  for (size_t i = (size_t)blockIdx.x * 256 + threadIdx.x; i < TOTAL; i += (size_t)gridDim.x * 256) {
    if (i < NZERO1) {
      ws[OFF_S1 + i] = 0.f;
    } else if (i < NZERO1 + NZERO2) {
      ws[OFF_S2 + (i - NZERO1)] = 0.f;
    } else if (i < NZERO1 + NZERO2 + NATTN) {
      size_t r = i - NZERO1 - NZERO2;
      size_t b = r / 50000, rem = r % 50000;
      out[OUT_ATTN + b * 100000 + 50000 + rem] = 0.f;
    } else if (i < NZERO1 + NZERO2 + NATTN + NKEYS) {
      int s = (int)(i - NZERO1 - NZERO2 - NATTN);
      uint2 F = threefry(0u, 1234u, 0u, (unsigned)s);
      uint2 kd1 = threefry(F.x, F.y, 0u, 0u);
      uint2 kd2 = threefry(F.x, F.y, 0u, 1u);
      uint2 kz1 = threefry(F.x, F.y, 0u, 2u);
      uint2 kz2 = threefry(F.x, F.y, 0u, 3u);
      keys[s * 8 + 0] = kd1.x; keys[s * 8 + 1] = kd1.y;
      keys[s * 8 + 2] = kd2.x; keys[s * 8 + 3] = kd2.y;
      keys[s * 8 + 4] = kz1.x; keys[s * 8 + 5] = kz1.y;
      keys[s * 8 + 6] = kz2.x; keys[s * 8 + 7] = kz2.y;
    } else {
      size_t r = i - NZERO1 - NZERO2 - NATTN - NKEYS;   // [0,4096)
      int a = (int)(r >> 5), kk = (int)(r & 31);
      float v = 0.f;
      if (kk < 31) {
        for (int f = 0; f < 32; ++f) v = fmaf(conv_w[f * 31 + kk], Wcp[f * 128 + a], v);
      }
      ws[OFF_CWT + r] = v;   // CWt[a][k], row stride 32
    }
  }
}

// ---------------------------------------------------------------------------
// k_encproj: encproj = e_outputs @ W_encproj + b  ([6400,512]@[512,128])
// ---------------------------------------------------------------------------
__global__ __launch_bounds__(256) void k_encproj(const float* __restrict__ e_out,
                                                 const float* __restrict__ Wenc,
                                                 const float* __restrict__ benc,
                                                 float* __restrict__ encproj) {
  __shared__ __align__(16) float xs[32 * 516];
  int t = threadIdx.x;
  int r0 = blockIdx.x * 32;
  for (int i = 0; i < 64; ++i) {
    int idx = t + 256 * i; int rb = idx >> 9, kk = idx & 511;
    xs[rb * 516 + kk] = e_out[(size_t)(r0 + rb) * 512 + kk];
  }
  __syncthreads();
  int a = t & 127, rh = t >> 7;
  float acc[16];
#pragma unroll
  for (int r = 0; r < 16; ++r) acc[r] = 0.f;
  const float4* xv = (const float4*)xs;
  for (int k4 = 0; k4 < 128; ++k4) {
    const float* wp = Wenc + (size_t)(k4 * 4) * 128 + a;
    float w0 = wp[0], w1 = wp[128], w2 = wp[256], w3 = wp[384];
#pragma unroll
    for (int r = 0; r < 16; ++r) {
      float4 x4 = xv[(rh * 16 + r) * 129 + k4];
      acc[r] = fmaf(x4.x, w0, acc[r]); acc[r] = fmaf(x4.y, w1, acc[r]);
      acc[r] = fmaf(x4.z, w2, acc[r]); acc[r] = fmaf(x4.w, w3, acc[r]);
    }
  }
  float bb = benc[a];
  for (int r = 0; r < 16; ++r)
    encproj[(size_t)(r0 + rh * 16 + r) * 128 + a] = acc[r] + bb;
}

// ---------------------------------------------------------------------------
// k_prenet: all 250 steps, exact dropout
// ---------------------------------------------------------------------------
__global__ __launch_bounds__(256) void k_prenet(const float* __restrict__ mel,
                                                const float* __restrict__ W1, const float* __restrict__ b1,
                                                const float* __restrict__ W2, const float* __restrict__ b2,
                                                const unsigned* __restrict__ keys,
                                                float* __restrict__ pre2_all) {
  int s = blockIdx.x, t = threadIdx.x;
  __shared__ __align__(16) float prev[32 * 80];
  __shared__ __align__(16) float p1[32 * 256];
  for (int i = 0; i < 10; ++i) {
    int idx = t + 256 * i;
    int bb = idx / 80, vv = idx % 80;
    prev[idx] = (s == 0) ? 0.f : mel[(size_t)bb * 40000 + (size_t)(2 * s - 1) * 80 + vv];
  }
  __syncthreads();
  unsigned kd10 = keys[s * 8 + 0], kd11 = keys[s * 8 + 1];
  unsigned kd20 = keys[s * 8 + 2], kd21 = keys[s * 8 + 3];
  float acc[32];
  float bias = b1[t];
#pragma unroll
  for (int b = 0; b < 32; ++b) acc[b] = bias;
  for (int k4 = 0; k4 < 20; ++k4) {
    const float* wp = W1 + (size_t)(k4 * 4) * 256 + t;
    float w0 = wp[0], w1 = wp[256], w2 = wp[512], w3 = wp[768];
#pragma unroll
    for (int b = 0; b < 32; ++b) {
      float4 x4 = *(const float4*)(prev + b * 80 + k4 * 4);
      acc[b] = fmaf(x4.x, w0, acc[b]); acc[b] = fmaf(x4.y, w1, acc[b]);
      acc[b] = fmaf(x4.z, w2, acc[b]); acc[b] = fmaf(x4.w, w3, acc[b]);
    }
  }
#pragma unroll
  for (int b = 0; b < 32; ++b) {
    float r = fmaxf(acc[b], 0.f);
    float u = rng_uniform(kd10, kd11, (unsigned)(b * 256 + t));
    p1[b * 256 + t] = (u < 0.5f) ? r * 2.f : 0.f;
  }
  __syncthreads();
  float bias2 = b2[t];
#pragma unroll
  for (int b = 0; b < 32; ++b) acc[b] = bias2;
  for (int k4 = 0; k4 < 64; ++k4) {
    const float* wp = W2 + (size_t)(k4 * 4) * 256 + t;
    float w0 = wp[0], w1 = wp[256], w2 = wp[512], w3 = wp[768];
#pragma unroll
    for (int b = 0; b < 32; ++b) {
      float4 x4 = *(const float4*)(p1 + b * 256 + k4 * 4);
      acc[b] = fmaf(x4.x, w0, acc[b]); acc[b] = fmaf(x4.y, w1, acc[b]);
      acc[b] = fmaf(x4.z, w2, acc[b]); acc[b] = fmaf(x4.w, w3, acc[b]);
    }
  }
  for (int b = 0; b < 32; ++b) {
    float r = fmaxf(acc[b], 0.f);
    float u = rng_uniform(kd20, kd21, (unsigned)(b * 256 + t));
    pre2_all[(size_t)(s * 32 + b) * 256 + t] = (u < 0.5f) ? r * 2.f : 0.f;
  }
}

// ---------------------------------------------------------------------------
// k_loop: persistent kernel, plain launch. grid 512 x 256, 5 gbar()/step.
// ---------------------------------------------------------------------------
struct KP {
  const float* e_out;
  const float* Wdec; const float* Wself;
  const float* Wys; const float* Wss; const float* Wgs; const float* bgs;
  const float* Wis; const float* Wss2; const float* bss2;
  float* ws; float* out;
};

__global__ __launch_bounds__(256, 2) void k_loop(KP p) {
  __shared__ __align__(16) float smem[32 * 132];   // 4224 floats
  const int blk = blockIdx.x, t = threadIdx.x;
  float* ws = p.ws;
  const float* encproj = ws + OFF_ENCPROJ;
  const float* cwt = ws + OFF_CWT;
  const unsigned* keys = (const unsigned*)(ws + OFF_KEYS);
  const float* pre2_all = ws + OFF_PRE2;
  float* g_all = ws + OFF_G;
  float* s2_all = ws + OFF_S2;
  float* s1buf = ws + OFF_S1;
  float* c1 = ws + OFF_C1;
  float* c2 = ws + OFF_C2;
  float* cum = ws + OFF_CUM;
  unsigned* flags = (unsigned*)(ws + OFF_BAR);
  unsigned* gen = flags + 512;
  float* part = ws + OFF_P;
  unsigned gcount = 0;

  for (int s = 0; s < NSTEP; ++s) {
    float* s1old = s1buf + (size_t)(s & 1) * 32768;
    float* s1new = s1buf + (size_t)((s + 1) & 1) * 32768;
    float* s2s = s2_all + (size_t)s * 32768;
    float* s2n = s2_all + (size_t)(s + 1) * 32768;
    float* gs = g_all + (size_t)s * 16384;

    // ==== PhA: full attention, one block per b (round-2-verified body) ====
    if (blk < 32) {
      int b = blk;
      float* dpp = smem;          // 256
      float* dpf = smem + 256;    // 128
      float* ca  = smem + 384;    // 232
      float* sc  = smem + 616;    // 200
      float* red = smem + 816;    // 8
      float* bcv = smem + 824;    // 2
      if (t < 232) ca[t] = (t >= 15 && t < 215) ? cum[b * 200 + (t - 15)] : 0.f;
      if (t < 200) sc[t] = 0.f;
      int a = t & 127, h = t >> 7;
      {
        const float* s2b = s2s + b * 1024 + h * 512;
        const float* wd = p.Wdec + (size_t)(h * 512) * 128 + a;
        float acc = 0.f;
        for (int d4 = 0; d4 < 128; ++d4) {
          float4 s4 = *(const float4*)(s2b + d4 * 4);
          acc = fmaf(s4.x, wd[(d4 * 4 + 0) * 128], acc);
          acc = fmaf(s4.y, wd[(d4 * 4 + 1) * 128], acc);
          acc = fmaf(s4.z, wd[(d4 * 4 + 2) * 128], acc);
          acc = fmaf(s4.w, wd[(d4 * 4 + 3) * 128], acc);
        }
        dpp[t] = acc;
      }
      __syncthreads();
      if (t < 128) dpf[t] = dpp[t] + dpp[t + 128];
      __syncthreads();
      float cwr[31];
#pragma unroll
      for (int k = 0; k < 31; ++k) cwr[k] = cwt[a * 32 + k];
      float wself_r = p.Wself[a];
      float dp_r = dpf[a];
      const float* epb = encproj + (size_t)(b * 200) * 128 + a;
      for (int ii = 0; ii < 25; ++ii) {
        int l0 = h + 8 * ii;
        float car[37];
#pragma unroll
        for (int m = 0; m < 37; ++m) car[m] = ca[l0 + m];
#pragma unroll
        for (int j = 0; j < 4; ++j) {
          int l = l0 + 2 * j;
          float conv = 0.f;
#pragma unroll
          for (int k = 0; k < 31; ++k) conv = fmaf(car[2 * j + k], cwr[k], conv);
          float e = tanhf(dp_r + epb[(size_t)l * 128] + conv);
          float v = e * wself_r;
#pragma unroll
          for (int off = 32; off > 0; off >>= 1) v += __shfl_xor(v, off, 64);
          if ((t & 63) == 0) atomicAdd(&sc[l], v);
        }
      }
      __syncthreads();
      float v = (t < 200) ? sc[t] : -3.4e38f;
#pragma unroll
      for (int off = 32; off > 0; off >>= 1) v = fmaxf(v, __shfl_xor(v, off, 64));
      if ((t & 63) == 0) red[t >> 6] = v;
      __syncthreads();
      if (t == 0) bcv[0] = fmaxf(fmaxf(red[0], red[1]), fmaxf(red[2], red[3]));
      __syncthreads();
      float mx = bcv[0];
      float ex = (t < 200) ? expf(sc[t] - mx) : 0.f;
      float sv = ex;
#pragma unroll
      for (int off = 32; off > 0; off >>= 1) sv += __shfl_xor(sv, off, 64);
      if ((t & 63) == 0) red[4 + (t >> 6)] = sv;
      __syncthreads();
      if (t == 0) bcv[1] = (red[4] + red[5]) + (red[6] + red[7]);
      __syncthreads();
      float denom = bcv[1];
      if (t < 200) {
        float al = ex / denom;
        sc[t] = al;
        cum[b * 200 + t] += al;
        p.out[OUT_ATTN + (size_t)s * 200 + (size_t)b * 100000 + t] = al;
      }
      __syncthreads();
      const float* eb = p.e_out + (size_t)b * 102400;
#pragma unroll 1
      for (int rep = 0; rep < 2; ++rep) {
        int d = t + 256 * rep;
        float acc = 0.f;
#pragma unroll 4
        for (int l = 0; l < 200; ++l) acc = fmaf(sc[l], eb[(size_t)l * 512 + d], acc);
        gs[b * 512 + d] = acc;
      }
    }
    gbar(flags, gen, ++gcount);

    // ==== PhB: LSTM1 GEMM partials (448 of 512 blocks, K=128 x 14 chunks) ====
    {
      int jt = blk & 31, c = blk >> 5;   // c 0..15, active c<14
      if (c < 14) {
        float* xs = smem;
        {
          int r = t >> 3, kq = t & 7;
          const float* src;
          if (c < 2)       src = pre2_all + (size_t)s * 8192 + r * 256 + c * 128;
          else if (c < 10) src = s1old + r * 1024 + (c - 2) * 128;
          else             src = gs + r * 512 + (c - 10) * 128;
          const float4* s4 = (const float4*)(src + kq * 16);
          float4* d4 = (float4*)(xs + r * 132 + kq * 16);
          d4[0] = s4[0]; d4[1] = s4[1]; d4[2] = s4[2]; d4[3] = s4[3];
        }
        const float* W0; int k0;
        if (c < 2)       { W0 = p.Wys; k0 = c * 128; }
        else if (c < 10) { W0 = p.Wss; k0 = (c - 2) * 128; }
        else             { W0 = p.Wgs; k0 = (c - 10) * 128; }
        __syncthreads();
        int jq = t & 31, bq = t >> 5, j = jt * 32 + jq;
        float4 acc[4];
        acc[0] = acc[1] = acc[2] = acc[3] = make_float4(0, 0, 0, 0);
        const float4* xv = (const float4*)xs;
        const float* Wb = W0 + (size_t)k0 * 4096 + j;
#pragma unroll 4
        for (int k4 = 0; k4 < 32; ++k4) {
          float4 xq[4];
          xq[0] = xv[(bq * 4 + 0) * 33 + k4];
          xq[1] = xv[(bq * 4 + 1) * 33 + k4];
          xq[2] = xv[(bq * 4 + 2) * 33 + k4];
          xq[3] = xv[(bq * 4 + 3) * 33 + k4];
          const float* wr = Wb + (size_t)(k4 * 4) * 4096;
#pragma unroll
          for (int ks = 0; ks < 4; ++ks) {
            float wi = wr[0], wf = wr[1024], wc = wr[2048], wo = wr[3072];
            wr += 4096;
#pragma unroll
            for (int r = 0; r < 4; ++r) {
              float xval = ((const float*)&xq[r])[ks];
              acc[r].x = fmaf(xval, wi, acc[r].x);
              acc[r].y = fmaf(xval, wf, acc[r].y);
              acc[r].z = fmaf(xval, wc, acc[r].z);
              acc[r].w = fmaf(xval, wo, acc[r].w);
            }
          }
        }
        float* pb = part + (size_t)c * 131072 + (size_t)(bq * 4) * 4096 + j;
#pragma unroll
        for (int r = 0; r < 4; ++r) {
          float* pr = pb + r * 4096;
          pr[0] = acc[r].x; pr[1024] = acc[r].y; pr[2048] = acc[r].z; pr[3072] = acc[r].w;
        }
      }
    }
    gbar(flags, gen, ++gcount);

    // ==== PhC: cell1 (blocks 0..127) ====
    if (blk < 128) {
      int e = blk * 256 + t;
      int j = e & 1023, b = e >> 10;
      float gi = p.bgs[j], gf = p.bgs[1024 + j], gc = p.bgs[2048 + j], go = p.bgs[3072 + j];
      const float* pc = part + (size_t)b * 4096 + j;
      for (int cc = 0; cc < 14; ++cc) {
        const float* p2 = pc + (size_t)cc * 131072;
        gi += p2[0]; gf += p2[1024]; gc += p2[2048]; go += p2[3072];
      }
      float u = rng_uniform(keys[s * 8 + 4], keys[s * 8 + 5], (unsigned)e);
      float m = floorf(u + 0.1f);
      float co = c1[e], so = s1old[e];
      float cn = fmaf(gatef(gf), co, gatef(gi) * tanhf(gc));
      float cnew = (m > 0.5f) ? co : cn;
      float sn = gatef(go) * tanhf(cnew);
      c1[e] = cnew;
      s1new[e] = (m > 0.5f) ? so : sn;
    }
    gbar(flags, gen, ++gcount);

    // ==== PhD: LSTM2 GEMM partials (512 blocks, K=128 x 16 chunks) ====
    {
      int jt = blk & 31, c = blk >> 5;   // 0..15
      float* xs = smem;
      {
        int r = t >> 3, kq = t & 7;
        const float* src = (c < 8) ? (s1new + r * 1024 + c * 128)
                                   : (s2s + r * 1024 + (c - 8) * 128);
        const float4* s4 = (const float4*)(src + kq * 16);
        float4* d4 = (float4*)(xs + r * 132 + kq * 16);
        d4[0] = s4[0]; d4[1] = s4[1]; d4[2] = s4[2]; d4[3] = s4[3];
      }
      const float* W0 = (c < 8) ? p.Wis : p.Wss2;
      int k0 = (c & 7) * 128;
      __syncthreads();
      int jq = t & 31, bq = t >> 5, j = jt * 32 + jq;
      float4 acc[4];
      acc[0] = acc[1] = acc[2] = acc[3] = make_float4(0, 0, 0, 0);
      const float4* xv = (const float4*)xs;
      const float* Wb = W0 + (size_t)k0 * 4096 + j;
#pragma unroll 4
      for (int k4 = 0; k4 < 32; ++k4) {
        float4 xq[4];
        xq[0] = xv[(bq * 4 + 0) * 33 + k4];
        xq[1] = xv[(bq * 4 + 1) * 33 + k4];
        xq[2] = xv[(bq * 4 + 2) * 33 + k4];
        xq[3] = xv[(bq * 4 + 3) * 33 + k4];
        const float* wr = Wb + (size_t)(k4 * 4) * 4096;
#pragma unroll
        for (int ks = 0; ks < 4; ++ks) {
          float wi = wr[0], wf = wr[1024], wc = wr[2048], wo = wr[3072];
          wr += 4096;
#pragma unroll
          for (int r = 0; r < 4; ++r) {
            float xval = ((const float*)&xq[r])[ks];
            acc[r].x = fmaf(xval, wi, acc[r].x);
            acc[r].y = fmaf(xval, wf, acc[r].y);
            acc[r].z = fmaf(xval, wc, acc[r].z);
            acc[r].w = fmaf(xval, wo, acc[r].w);
          }
        }
      }
      float* pb = part + (size_t)c * 131072 + (size_t)(bq * 4) * 4096 + j;
#pragma unroll
      for (int r = 0; r < 4; ++r) {
        float* pr = pb + r * 4096;
        pr[0] = acc[r].x; pr[1024] = acc[r].y; pr[2048] = acc[r].z; pr[3072] = acc[r].w;
      }
    }
    gbar(flags, gen, ++gcount);

    // ==== PhE: cell2 (blocks 0..127) ====
    if (blk < 128) {
      int e = blk * 256 + t;
      int j = e & 1023, b = e >> 10;
      float gi = p.bss2[j], gf = p.bss2[1024 + j], gc = p.bss2[2048 + j], go = p.bss2[3072 + j];
      const float* pc = part + (size_t)b * 4096 + j;
      for (int cc = 0; cc < 16; ++cc) {
        const float* p2 = pc + (size_t)cc * 131072;
        gi += p2[0]; gf += p2[1024]; gc += p2[2048]; go += p2[3072];
      }
      float u = rng_uniform(keys[s * 8 + 6], keys[s * 8 + 7], (unsigned)e);
      float m = floorf(u + 0.1f);
      float co = c2[e], so = s2s[e];
      float cn = fmaf(gatef(gf), co, gatef(gi) * tanhf(gc));
      float cnew = (m > 0.5f) ? co : cn;
      float sn = gatef(go) * tanhf(cnew);
      c2[e] = cnew;
      s2n[e] = (m > 0.5f) ? so : sn;
    }
    gbar(flags, gen, ++gcount);
  }
}

// ---------------------------------------------------------------------------
// k_frame: deferred frame/token projection. grid 250.
// ---------------------------------------------------------------------------
__global__ __launch_bounds__(256) void k_frame(const float* __restrict__ s2_all,
                                               const float* __restrict__ g_all,
                                               const float* __restrict__ Wf,
                                               const float* __restrict__ bf,
                                               const float* __restrict__ Wt,
                                               const float* __restrict__ bt,
                                               float* __restrict__ out_frame,
                                               float* __restrict__ out_tok) {
  int s = blockIdx.x, t = threadIdx.x;
  __shared__ __align__(16) float xs[32 * 516];
  int b = t >> 3, ci = t & 7;
  int tb = t >> 1, tr = t & 1;
  float4 acc[5];
#pragma unroll
  for (int r = 0; r < 5; ++r) acc[r] = make_float4(0, 0, 0, 0);
  float tok = 0.f;
  for (int ch = 0; ch < 3; ++ch) {
    for (int i = 0; i < 64; ++i) {
      int idx = t + 256 * i;
      int rb = idx >> 9, kk = idx & 511;
      float vsrc = (ch < 2) ? s2_all[(size_t)(s + 1) * 32768 + rb * 1024 + ch * 512 + kk]
                            : g_all[(size_t)s * 16384 + rb * 512 + kk];
      xs[rb * 516 + kk] = vsrc;
    }
    __syncthreads();
    const float4* xv = (const float4*)xs;
    for (int k4 = 0; k4 < 128; ++k4) {
      float4 x4 = xv[b * 129 + k4];
      int kglob = ch * 512 + k4 * 4;
#pragma unroll
      for (int rep = 0; rep < 5; ++rep) {
        int c4 = ci * 4 + rep * 32;
        const float* wrow = Wf + (size_t)kglob * 160 + c4;
        float4 w0 = *(const float4*)(wrow);
        float4 w1 = *(const float4*)(wrow + 160);
        float4 w2 = *(const float4*)(wrow + 320);
        float4 w3 = *(const float4*)(wrow + 480);
        FMA4(acc[rep], x4.x, w0); FMA4(acc[rep], x4.y, w1);
        FMA4(acc[rep], x4.z, w2); FMA4(acc[rep], x4.w, w3);
      }
      if (t < 64) {
        float4 xt = xv[tb * 129 + k4];
        tok = fmaf(xt.x, Wt[(size_t)(kglob + 0) * 2 + tr], tok);
        tok = fmaf(xt.y, Wt[(size_t)(kglob + 1) * 2 + tr], tok);
        tok = fmaf(xt.z, Wt[(size_t)(kglob + 2) * 2 + tr], tok);
        tok = fmaf(xt.w, Wt[(size_t)(kglob + 3) * 2 + tr], tok);
      }
    }
    __syncthreads();
  }
#pragma unroll
  for (int rep = 0; rep < 5; ++rep) {
    float vals[4] = {acc[rep].x, acc[rep].y, acc[rep].z, acc[rep].w};
#pragma unroll
    for (int jj = 0; jj < 4; ++jj) {
      int cc = ci * 4 + rep * 32 + jj;
      float val = vals[jj] + bf[cc];
      int row = 2 * s + (cc >= 80 ? 1 : 0);
      int col = cc - (cc >= 80 ? 80 : 0);
      out_frame[(size_t)b * 40000 + (size_t)row * 80 + col] = val;
    }
  }
  if (t < 64) out_tok[(size_t)tb * 500 + 2 * s + tr] = tok + bt[tr];
}

// ---------------------------------------------------------------------------
extern "C" void kernel_launch(void* const* d_in, const int* in_sizes, int n_in,
                              void* d_out_v, int out_size, void* d_ws, size_t ws_size,
                              hipStream_t stream) {
  (void)in_sizes; (void)n_in; (void)out_size; (void)ws_size;
  const float* mel      = (const float*)d_in[0];
  const float* e_out    = (const float*)d_in[1];
  const float* conv_w   = (const float*)d_in[2];
  const float* Wcp      = (const float*)d_in[3];
  const float* Wenc     = (const float*)d_in[4];
  const float* benc     = (const float*)d_in[5];
  const float* Wdec     = (const float*)d_in[6];
  const float* Wself    = (const float*)d_in[7];
  const float* Wp1      = (const float*)d_in[8];
  const float* bp1      = (const float*)d_in[9];
  const float* Wp2      = (const float*)d_in[10];
  const float* bp2      = (const float*)d_in[11];
  const float* Wys      = (const float*)d_in[12];
  const float* Wss      = (const float*)d_in[13];
  const float* Wgs      = (const float*)d_in[14];
  const float* bgs      = (const float*)d_in[15];
  const float* Wis      = (const float*)d_in[16];
  const float* Wss2     = (const float*)d_in[17];
  const float* bss2     = (const float*)d_in[18];
  const float* Wf       = (const float*)d_in[19];
  const float* bf       = (const float*)d_in[20];
  const float* Wt       = (const float*)d_in[21];
  const float* bt       = (const float*)d_in[22];
  float* ws  = (float*)d_ws;
  float* out = (float*)d_out_v;
  const unsigned* keys = (const unsigned*)(ws + OFF_KEYS);

  hipLaunchKernelGGL(k_init, dim3(1024), dim3(256), 0, stream, ws, out, conv_w, Wcp);
  hipLaunchKernelGGL(k_encproj, dim3(200), dim3(256), 0, stream, e_out, Wenc, benc, ws + OFF_ENCPROJ);
  hipLaunchKernelGGL(k_prenet, dim3(250), dim3(256), 0, stream, mel, Wp1, bp1, Wp2, bp2, keys, ws + OFF_PRE2);

  KP kp;
  kp.e_out = e_out; kp.Wdec = Wdec; kp.Wself = Wself;
  kp.Wys = Wys; kp.Wss = Wss; kp.Wgs = Wgs; kp.bgs = bgs;
  kp.Wis = Wis; kp.Wss2 = Wss2; kp.bss2 = bss2;
  kp.ws = ws; kp.out = out;
  hipLaunchKernelGGL(k_loop, dim3(GRID), dim3(256), 0, stream, kp);

  hipLaunchKernelGGL(k_frame, dim3(250), dim3(256), 0, stream,
                     ws + OFF_S2, ws + OFF_G, Wf, bf, Wt, bt, out, out + OUT_TOK);
}

// Round 9
// 98248.114 us; speedup vs baseline: 3.9120x; 3.4137x over previous
//
#include <hip/hip_runtime.h>
#include <cstdint>
#include <cstddef>

// ---------------------------------------------------------------------------
// Tacotron2 decoder, MI355X. Round 9: identical to round 8 (PASSING, 335ms)
// except the grid barrier internals. r7/r8 data: ~300us/barrier in BOTH
// barrier designs = N serialized agent-scope accesses to ONE line (~0.5us
// each). Fix: 128B-strided flags AND a 64-line gen broadcast (8 pollers/line),
// RELAXED polling (no per-poll cache ops), exactly 2 threadfence/block/barrier.
// ---------------------------------------------------------------------------

static constexpr int NSTEP = 250;
static constexpr unsigned GRID = 512;

// workspace offsets (floats). total = 17,448,960 floats (~69.8 MB)
static constexpr size_t OFF_ENCPROJ = 0;               // 819200
static constexpr size_t OFF_CWT     = 819200;          // 4096
static constexpr size_t OFF_KEYS    = 823296;          // 2048 (250*8 uints)
static constexpr size_t OFF_PRE2    = 825344;          // 2048000
static constexpr size_t OFF_G       = 2873344;         // 4096000
static constexpr size_t OFF_S2      = 6969344;         // 251*32768 = 8224768
static constexpr size_t OFF_S1      = 15194112;        // 65536 (ping-pong)
static constexpr size_t OFF_C1      = 15259648;        // 32768
static constexpr size_t OFF_C2      = 15292416;        // 32768
static constexpr size_t OFF_CUM     = 15325184;        // 6400 used
static constexpr size_t OFF_P       = 15333376;        // 16*131072 (part overlaid)
static constexpr size_t OFF_BAR     = 17430528;        // 18432 uints: flags[512*32], genarr[64*32]

// d_out offsets (floats)
static constexpr size_t OUT_TOK  = 1280000;
static constexpr size_t OUT_ATTN = 1296000;

// ---------------------------------------------------------------------------
// Threefry-2x32 (JAX partitionable split — verified bit-exact rounds 2/4/7/8)
// ---------------------------------------------------------------------------
__device__ __forceinline__ uint2 threefry(unsigned k0, unsigned k1, unsigned c0, unsigned c1) {
  unsigned ks2 = k0 ^ k1 ^ 0x1BD11BDAu;
  unsigned x0 = c0 + k0, x1 = c1 + k1;
#define TFR(rot) { x0 += x1; x1 = (x1 << (rot)) | (x1 >> (32 - (rot))); x1 ^= x0; }
  TFR(13) TFR(15) TFR(26) TFR(6)   x0 += k1;  x1 += ks2 + 1u;
  TFR(17) TFR(29) TFR(16) TFR(24)  x0 += ks2; x1 += k0 + 2u;
  TFR(13) TFR(15) TFR(26) TFR(6)   x0 += k0;  x1 += k1 + 3u;
  TFR(17) TFR(29) TFR(16) TFR(24)  x0 += k1;  x1 += ks2 + 4u;
  TFR(13) TFR(15) TFR(26) TFR(6)   x0 += ks2; x1 += k0 + 5u;
#undef TFR
  return make_uint2(x0, x1);
}

__device__ __forceinline__ float u32_to_uniform(unsigned b) {
  return __uint_as_float((b >> 9) | 0x3f800000u) - 1.0f;
}

__device__ __forceinline__ float rng_uniform(unsigned k0, unsigned k1, unsigned i) {
  uint2 h = threefry(k0, k1, 0u, i);
  return u32_to_uniform(h.x ^ h.y);
}

__device__ __forceinline__ float gatef(float x) { return tanhf(x * 0.5f) * 0.5f + 0.5f; }

#define FMA4(A, S, W) { (A).x = fmaf((S), (W).x, (A).x); (A).y = fmaf((S), (W).y, (A).y); \
                        (A).z = fmaf((S), (W).z, (A).z); (A).w = fmaf((S), (W).w, (A).w); }

// ---------------------------------------------------------------------------
// De-hotspotted grid barrier.
//  flags: 512 slots, 128B stride (1 line per block). genarr: 64 slots, 128B
//  stride; block i polls slot (i&63) -> ~8 pollers/line.
//  RELAXED polls (no per-poll cache maintenance); 2 threadfence/block/barrier
//  give the release/acquire chain: worker -> block0 -> worker.
// ---------------------------------------------------------------------------
__device__ __forceinline__ void gbar(unsigned* flags, unsigned* genarr, unsigned g) {
  __syncthreads();
  if (blockIdx.x == 0) {
    int t = threadIdx.x;
    __threadfence();   // release block 0's own phase writes
#pragma unroll
    for (int rep = 0; rep < 2; ++rep) {
      int f = t + rep * 256;
      if (f > 0) {
        while (__hip_atomic_load(&flags[f * 32], __ATOMIC_RELAXED, __HIP_MEMORY_SCOPE_AGENT) < g) {
          __builtin_amdgcn_s_sleep(1);
        }
      }
    }
    __threadfence();   // acquire all workers' writes / release before broadcast
    __syncthreads();
    if (t < 64) {
      __hip_atomic_store(&genarr[t * 32], g, __ATOMIC_RELAXED, __HIP_MEMORY_SCOPE_AGENT);
    }
  } else {
    if (threadIdx.x == 0) {
      __threadfence();   // release this block's phase writes
      __hip_atomic_store(&flags[blockIdx.x * 32], g, __ATOMIC_RELAXED, __HIP_MEMORY_SCOPE_AGENT);
      unsigned slot = (unsigned)(blockIdx.x & 63) * 32u;
      while (__hip_atomic_load(&genarr[slot], __ATOMIC_RELAXED, __HIP_MEMORY_SCOPE_AGENT) < g) {
        __builtin_amdgcn_s_sleep(8);
      }
      __threadfence();   // acquire
    }
  }
  __syncthreads();
}

// ---------------------------------------------------------------------------
// k_init: zero state/cum/bar/attn-tail, RNG keys, fused conv weights CWt
// ---------------------------------------------------------------------------
__global__ __launch_bounds__(256) void k_init(float* __restrict__ ws, float* __restrict__ out,
                                              const float* __restrict__ conv_w,
                                              const float* __restrict__ Wcp) {
  const size_t NZERO1 = 139264;   // [OFF_S1, OFF_P): s1 x2, c1, c2, cum
  const size_t NZERO2 = 32768;    // s2_all slot 0
  const size_t NATTN  = 1600000;  // attn rows 250..499
  const size_t NKEYS  = 250;
  const size_t NCWT   = 4096;
  const size_t NBAR   = 18432;    // flags + genarr
  const size_t TOTAL  = NZERO1 + NZERO2 + NATTN + NKEYS + NCWT + NBAR;
  unsigned* keys = (unsigned*)(ws + OFF_KEYS);
  for (size_t i = (size_t)blockIdx.x * 256 + threadIdx.x; i < TOTAL; i += (size_t)gridDim.x * 256) {
    if (i < NZERO1) {
      ws[OFF_S1 + i] = 0.f;
    } else if (i < NZERO1 + NZERO2) {
      ws[OFF_S2 + (i - NZERO1)] = 0.f;
    } else if (i < NZERO1 + NZERO2 + NATTN) {
      size_t r = i - NZERO1 - NZERO2;
      size_t b = r / 50000, rem = r % 50000;
      out[OUT_ATTN + b * 100000 + 50000 + rem] = 0.f;
    } else if (i < NZERO1 + NZERO2 + NATTN + NKEYS) {
      int s = (int)(i - NZERO1 - NZERO2 - NATTN);
      uint2 F = threefry(0u, 1234u, 0u, (unsigned)s);
      uint2 kd1 = threefry(F.x, F.y, 0u, 0u);
      uint2 kd2 = threefry(F.x, F.y, 0u, 1u);
      uint2 kz1 = threefry(F.x, F.y, 0u, 2u);
      uint2 kz2 = threefry(F.x, F.y, 0u, 3u);
      keys[s * 8 + 0] = kd1.x; keys[s * 8 + 1] = kd1.y;
      keys[s * 8 + 2] = kd2.x; keys[s * 8 + 3] = kd2.y;
      keys[s * 8 + 4] = kz1.x; keys[s * 8 + 5] = kz1.y;
      keys[s * 8 + 6] = kz2.x; keys[s * 8 + 7] = kz2.y;
    } else if (i < NZERO1 + NZERO2 + NATTN + NKEYS + NCWT) {
      size_t r = i - NZERO1 - NZERO2 - NATTN - NKEYS;   // [0,4096)
      int a = (int)(r >> 5), kk = (int)(r & 31);
      float v = 0.f;
      if (kk < 31) {
        for (int f = 0; f < 32; ++f) v = fmaf(conv_w[f * 31 + kk], Wcp[f * 128 + a], v);
      }
      ws[OFF_CWT + r] = v;   // CWt[a][k], row stride 32
    } else {
      size_t r = i - NZERO1 - NZERO2 - NATTN - NKEYS - NCWT;   // [0,18432)
      ((unsigned*)(ws + OFF_BAR))[r] = 0u;
    }
  }
}

// ---------------------------------------------------------------------------
// k_encproj: encproj = e_outputs @ W_encproj + b  ([6400,512]@[512,128])
// ---------------------------------------------------------------------------
__global__ __launch_bounds__(256) void k_encproj(const float* __restrict__ e_out,
                                                 const float* __restrict__ Wenc,
                                                 const float* __restrict__ benc,
                                                 float* __restrict__ encproj) {
  __shared__ __align__(16) float xs[32 * 516];
  int t = threadIdx.x;
  int r0 = blockIdx.x * 32;
  for (int i = 0; i < 64; ++i) {
    int idx = t + 256 * i; int rb = idx >> 9, kk = idx & 511;
    xs[rb * 516 + kk] = e_out[(size_t)(r0 + rb) * 512 + kk];
  }
  __syncthreads();
  int a = t & 127, rh = t >> 7;
  float acc[16];
#pragma unroll
  for (int r = 0; r < 16; ++r) acc[r] = 0.f;
  const float4* xv = (const float4*)xs;
  for (int k4 = 0; k4 < 128; ++k4) {
    const float* wp = Wenc + (size_t)(k4 * 4) * 128 + a;
    float w0 = wp[0], w1 = wp[128], w2 = wp[256], w3 = wp[384];
#pragma unroll
    for (int r = 0; r < 16; ++r) {
      float4 x4 = xv[(rh * 16 + r) * 129 + k4];
      acc[r] = fmaf(x4.x, w0, acc[r]); acc[r] = fmaf(x4.y, w1, acc[r]);
      acc[r] = fmaf(x4.z, w2, acc[r]); acc[r] = fmaf(x4.w, w3, acc[r]);
    }
  }
  float bb = benc[a];
  for (int r = 0; r < 16; ++r)
    encproj[(size_t)(r0 + rh * 16 + r) * 128 + a] = acc[r] + bb;
}

// ---------------------------------------------------------------------------
// k_prenet: all 250 steps, exact dropout
// ---------------------------------------------------------------------------
__global__ __launch_bounds__(256) void k_prenet(const float* __restrict__ mel,
                                                const float* __restrict__ W1, const float* __restrict__ b1,
                                                const float* __restrict__ W2, const float* __restrict__ b2,
                                                const unsigned* __restrict__ keys,
                                                float* __restrict__ pre2_all) {
  int s = blockIdx.x, t = threadIdx.x;
  __shared__ __align__(16) float prev[32 * 80];
  __shared__ __align__(16) float p1[32 * 256];
  for (int i = 0; i < 10; ++i) {
    int idx = t + 256 * i;
    int bb = idx / 80, vv = idx % 80;
    prev[idx] = (s == 0) ? 0.f : mel[(size_t)bb * 40000 + (size_t)(2 * s - 1) * 80 + vv];
  }
  __syncthreads();
  unsigned kd10 = keys[s * 8 + 0], kd11 = keys[s * 8 + 1];
  unsigned kd20 = keys[s * 8 + 2], kd21 = keys[s * 8 + 3];
  float acc[32];
  float bias = b1[t];
#pragma unroll
  for (int b = 0; b < 32; ++b) acc[b] = bias;
  for (int k4 = 0; k4 < 20; ++k4) {
    const float* wp = W1 + (size_t)(k4 * 4) * 256 + t;
    float w0 = wp[0], w1 = wp[256], w2 = wp[512], w3 = wp[768];
#pragma unroll
    for (int b = 0; b < 32; ++b) {
      float4 x4 = *(const float4*)(prev + b * 80 + k4 * 4);
      acc[b] = fmaf(x4.x, w0, acc[b]); acc[b] = fmaf(x4.y, w1, acc[b]);
      acc[b] = fmaf(x4.z, w2, acc[b]); acc[b] = fmaf(x4.w, w3, acc[b]);
    }
  }
#pragma unroll
  for (int b = 0; b < 32; ++b) {
    float r = fmaxf(acc[b], 0.f);
    float u = rng_uniform(kd10, kd11, (unsigned)(b * 256 + t));
    p1[b * 256 + t] = (u < 0.5f) ? r * 2.f : 0.f;
  }
  __syncthreads();
  float bias2 = b2[t];
#pragma unroll
  for (int b = 0; b < 32; ++b) acc[b] = bias2;
  for (int k4 = 0; k4 < 64; ++k4) {
    const float* wp = W2 + (size_t)(k4 * 4) * 256 + t;
    float w0 = wp[0], w1 = wp[256], w2 = wp[512], w3 = wp[768];
#pragma unroll
    for (int b = 0; b < 32; ++b) {
      float4 x4 = *(const float4*)(p1 + b * 256 + k4 * 4);
      acc[b] = fmaf(x4.x, w0, acc[b]); acc[b] = fmaf(x4.y, w1, acc[b]);
      acc[b] = fmaf(x4.z, w2, acc[b]); acc[b] = fmaf(x4.w, w3, acc[b]);
    }
  }
  for (int b = 0; b < 32; ++b) {
    float r = fmaxf(acc[b], 0.f);
    float u = rng_uniform(kd20, kd21, (unsigned)(b * 256 + t));
    pre2_all[(size_t)(s * 32 + b) * 256 + t] = (u < 0.5f) ? r * 2.f : 0.f;
  }
}

// ---------------------------------------------------------------------------
// k_loop: persistent kernel, plain launch. grid 512 x 256, 5 gbar()/step.
// ---------------------------------------------------------------------------
struct KP {
  const float* e_out;
  const float* Wdec; const float* Wself;
  const float* Wys; const float* Wss; const float* Wgs; const float* bgs;
  const float* Wis; const float* Wss2; const float* bss2;
  float* ws; float* out;
};

__global__ __launch_bounds__(256, 2) void k_loop(KP p) {
  __shared__ __align__(16) float smem[32 * 132];   // 4224 floats
  const int blk = blockIdx.x, t = threadIdx.x;
  float* ws = p.ws;
  const float* encproj = ws + OFF_ENCPROJ;
  const float* cwt = ws + OFF_CWT;
  const unsigned* keys = (const unsigned*)(ws + OFF_KEYS);
  const float* pre2_all = ws + OFF_PRE2;
  float* g_all = ws + OFF_G;
  float* s2_all = ws + OFF_S2;
  float* s1buf = ws + OFF_S1;
  float* c1 = ws + OFF_C1;
  float* c2 = ws + OFF_C2;
  float* cum = ws + OFF_CUM;
  unsigned* flags = (unsigned*)(ws + OFF_BAR);
  unsigned* genarr = flags + 512 * 32;
  float* part = ws + OFF_P;
  unsigned gcount = 0;

  for (int s = 0; s < NSTEP; ++s) {
    float* s1old = s1buf + (size_t)(s & 1) * 32768;
    float* s1new = s1buf + (size_t)((s + 1) & 1) * 32768;
    float* s2s = s2_all + (size_t)s * 32768;
    float* s2n = s2_all + (size_t)(s + 1) * 32768;
    float* gs = g_all + (size_t)s * 16384;

    // ==== PhA: full attention, one block per b (round-2-verified body) ====
    if (blk < 32) {
      int b = blk;
      float* dpp = smem;          // 256
      float* dpf = smem + 256;    // 128
      float* ca  = smem + 384;    // 232
      float* sc  = smem + 616;    // 200
      float* red = smem + 816;    // 8
      float* bcv = smem + 824;    // 2
      if (t < 232) ca[t] = (t >= 15 && t < 215) ? cum[b * 200 + (t - 15)] : 0.f;
      if (t < 200) sc[t] = 0.f;
      int a = t & 127, h = t >> 7;
      {
        const float* s2b = s2s + b * 1024 + h * 512;
        const float* wd = p.Wdec + (size_t)(h * 512) * 128 + a;
        float acc = 0.f;
        for (int d4 = 0; d4 < 128; ++d4) {
          float4 s4 = *(const float4*)(s2b + d4 * 4);
          acc = fmaf(s4.x, wd[(d4 * 4 + 0) * 128], acc);
          acc = fmaf(s4.y, wd[(d4 * 4 + 1) * 128], acc);
          acc = fmaf(s4.z, wd[(d4 * 4 + 2) * 128], acc);
          acc = fmaf(s4.w, wd[(d4 * 4 + 3) * 128], acc);
        }
        dpp[t] = acc;
      }
      __syncthreads();
      if (t < 128) dpf[t] = dpp[t] + dpp[t + 128];
      __syncthreads();
      float cwr[31];
#pragma unroll
      for (int k = 0; k < 31; ++k) cwr[k] = cwt[a * 32 + k];
      float wself_r = p.Wself[a];
      float dp_r = dpf[a];
      const float* epb = encproj + (size_t)(b * 200) * 128 + a;
      for (int ii = 0; ii < 25; ++ii) {
        int l0 = h + 8 * ii;
        float car[37];
#pragma unroll
        for (int m = 0; m < 37; ++m) car[m] = ca[l0 + m];
#pragma unroll
        for (int j = 0; j < 4; ++j) {
          int l = l0 + 2 * j;
          float conv = 0.f;
#pragma unroll
          for (int k = 0; k < 31; ++k) conv = fmaf(car[2 * j + k], cwr[k], conv);
          float e = tanhf(dp_r + epb[(size_t)l * 128] + conv);
          float v = e * wself_r;
#pragma unroll
          for (int off = 32; off > 0; off >>= 1) v += __shfl_xor(v, off, 64);
          if ((t & 63) == 0) atomicAdd(&sc[l], v);
        }
      }
      __syncthreads();
      float v = (t < 200) ? sc[t] : -3.4e38f;
#pragma unroll
      for (int off = 32; off > 0; off >>= 1) v = fmaxf(v, __shfl_xor(v, off, 64));
      if ((t & 63) == 0) red[t >> 6] = v;
      __syncthreads();
      if (t == 0) bcv[0] = fmaxf(fmaxf(red[0], red[1]), fmaxf(red[2], red[3]));
      __syncthreads();
      float mx = bcv[0];
      float ex = (t < 200) ? expf(sc[t] - mx) : 0.f;
      float sv = ex;
#pragma unroll
      for (int off = 32; off > 0; off >>= 1) sv += __shfl_xor(sv, off, 64);
      if ((t & 63) == 0) red[4 + (t >> 6)] = sv;
      __syncthreads();
      if (t == 0) bcv[1] = (red[4] + red[5]) + (red[6] + red[7]);
      __syncthreads();
      float denom = bcv[1];
      if (t < 200) {
        float al = ex / denom;
        sc[t] = al;
        cum[b * 200 + t] += al;
        p.out[OUT_ATTN + (size_t)s * 200 + (size_t)b * 100000 + t] = al;
      }
      __syncthreads();
      const float* eb = p.e_out + (size_t)b * 102400;
#pragma unroll 1
      for (int rep = 0; rep < 2; ++rep) {
        int d = t + 256 * rep;
        float acc = 0.f;
#pragma unroll 4
        for (int l = 0; l < 200; ++l) acc = fmaf(sc[l], eb[(size_t)l * 512 + d], acc);
        gs[b * 512 + d] = acc;
      }
    }
    gbar(flags, genarr, ++gcount);

    // ==== PhB: LSTM1 GEMM partials (448 of 512 blocks, K=128 x 14 chunks) ====
    {
      int jt = blk & 31, c = blk >> 5;   // c 0..15, active c<14
      if (c < 14) {
        float* xs = smem;
        {
          int r = t >> 3, kq = t & 7;
          const float* src;
          if (c < 2)       src = pre2_all + (size_t)s * 8192 + r * 256 + c * 128;
          else if (c < 10) src = s1old + r * 1024 + (c - 2) * 128;
          else             src = gs + r * 512 + (c - 10) * 128;
          const float4* s4 = (const float4*)(src + kq * 16);
          float4* d4 = (float4*)(xs + r * 132 + kq * 16);
          d4[0] = s4[0]; d4[1] = s4[1]; d4[2] = s4[2]; d4[3] = s4[3];
        }
        const float* W0; int k0;
        if (c < 2)       { W0 = p.Wys; k0 = c * 128; }
        else if (c < 10) { W0 = p.Wss; k0 = (c - 2) * 128; }
        else             { W0 = p.Wgs; k0 = (c - 10) * 128; }
        __syncthreads();
        int jq = t & 31, bq = t >> 5, j = jt * 32 + jq;
        float4 acc[4];
        acc[0] = acc[1] = acc[2] = acc[3] = make_float4(0, 0, 0, 0);
        const float4* xv = (const float4*)xs;
        const float* Wb = W0 + (size_t)k0 * 4096 + j;
#pragma unroll 4
        for (int k4 = 0; k4 < 32; ++k4) {
          float4 xq[4];
          xq[0] = xv[(bq * 4 + 0) * 33 + k4];
          xq[1] = xv[(bq * 4 + 1) * 33 + k4];
          xq[2] = xv[(bq * 4 + 2) * 33 + k4];
          xq[3] = xv[(bq * 4 + 3) * 33 + k4];
          const float* wr = Wb + (size_t)(k4 * 4) * 4096;
#pragma unroll
          for (int ks = 0; ks < 4; ++ks) {
            float wi = wr[0], wf = wr[1024], wc = wr[2048], wo = wr[3072];
            wr += 4096;
#pragma unroll
            for (int r = 0; r < 4; ++r) {
              float xval = ((const float*)&xq[r])[ks];
              acc[r].x = fmaf(xval, wi, acc[r].x);
              acc[r].y = fmaf(xval, wf, acc[r].y);
              acc[r].z = fmaf(xval, wc, acc[r].z);
              acc[r].w = fmaf(xval, wo, acc[r].w);
            }
          }
        }
        float* pb = part + (size_t)c * 131072 + (size_t)(bq * 4) * 4096 + j;
#pragma unroll
        for (int r = 0; r < 4; ++r) {
          float* pr = pb + r * 4096;
          pr[0] = acc[r].x; pr[1024] = acc[r].y; pr[2048] = acc[r].z; pr[3072] = acc[r].w;
        }
      }
    }
    gbar(flags, genarr, ++gcount);

    // ==== PhC: cell1 (blocks 0..127) ====
    if (blk < 128) {
      int e = blk * 256 + t;
      int j = e & 1023, b = e >> 10;
      float gi = p.bgs[j], gf = p.bgs[1024 + j], gc = p.bgs[2048 + j], go = p.bgs[3072 + j];
      const float* pc = part + (size_t)b * 4096 + j;
      for (int cc = 0; cc < 14; ++cc) {
        const float* p2 = pc + (size_t)cc * 131072;
        gi += p2[0]; gf += p2[1024]; gc += p2[2048]; go += p2[3072];
      }
      float u = rng_uniform(keys[s * 8 + 4], keys[s * 8 + 5], (unsigned)e);
      float m = floorf(u + 0.1f);
      float co = c1[e], so = s1old[e];
      float cn = fmaf(gatef(gf), co, gatef(gi) * tanhf(gc));
      float cnew = (m > 0.5f) ? co : cn;
      float sn = gatef(go) * tanhf(cnew);
      c1[e] = cnew;
      s1new[e] = (m > 0.5f) ? so : sn;
    }
    gbar(flags, genarr, ++gcount);

    // ==== PhD: LSTM2 GEMM partials (512 blocks, K=128 x 16 chunks) ====
    {
      int jt = blk & 31, c = blk >> 5;   // 0..15
      float* xs = smem;
      {
        int r = t >> 3, kq = t & 7;
        const float* src = (c < 8) ? (s1new + r * 1024 + c * 128)
                                   : (s2s + r * 1024 + (c - 8) * 128);
        const float4* s4 = (const float4*)(src + kq * 16);
        float4* d4 = (float4*)(xs + r * 132 + kq * 16);
        d4[0] = s4[0]; d4[1] = s4[1]; d4[2] = s4[2]; d4[3] = s4[3];
      }
      const float* W0 = (c < 8) ? p.Wis : p.Wss2;
      int k0 = (c & 7) * 128;
      __syncthreads();
      int jq = t & 31, bq = t >> 5, j = jt * 32 + jq;
      float4 acc[4];
      acc[0] = acc[1] = acc[2] = acc[3] = make_float4(0, 0, 0, 0);
      const float4* xv = (const float4*)xs;
      const float* Wb = W0 + (size_t)k0 * 4096 + j;
#pragma unroll 4
      for (int k4 = 0; k4 < 32; ++k4) {
        float4 xq[4];
        xq[0] = xv[(bq * 4 + 0) * 33 + k4];
        xq[1] = xv[(bq * 4 + 1) * 33 + k4];
        xq[2] = xv[(bq * 4 + 2) * 33 + k4];
        xq[3] = xv[(bq * 4 + 3) * 33 + k4];
        const float* wr = Wb + (size_t)(k4 * 4) * 4096;
#pragma unroll
        for (int ks = 0; ks < 4; ++ks) {
          float wi = wr[0], wf = wr[1024], wc = wr[2048], wo = wr[3072];
          wr += 4096;
#pragma unroll
          for (int r = 0; r < 4; ++r) {
            float xval = ((const float*)&xq[r])[ks];
            acc[r].x = fmaf(xval, wi, acc[r].x);
            acc[r].y = fmaf(xval, wf, acc[r].y);
            acc[r].z = fmaf(xval, wc, acc[r].z);
            acc[r].w = fmaf(xval, wo, acc[r].w);
          }
        }
      }
      float* pb = part + (size_t)c * 131072 + (size_t)(bq * 4) * 4096 + j;
#pragma unroll
      for (int r = 0; r < 4; ++r) {
        float* pr = pb + r * 4096;
        pr[0] = acc[r].x; pr[1024] = acc[r].y; pr[2048] = acc[r].z; pr[3072] = acc[r].w;
      }
    }
    gbar(flags, genarr, ++gcount);

    // ==== PhE: cell2 (blocks 0..127) ====
    if (blk < 128) {
      int e = blk * 256 + t;
      int j = e & 1023, b = e >> 10;
      float gi = p.bss2[j], gf = p.bss2[1024 + j], gc = p.bss2[2048 + j], go = p.bss2[3072 + j];
      const float* pc = part + (size_t)b * 4096 + j;
      for (int cc = 0; cc < 16; ++cc) {
        const float* p2 = pc + (size_t)cc * 131072;
        gi += p2[0]; gf += p2[1024]; gc += p2[2048]; go += p2[3072];
      }
      float u = rng_uniform(keys[s * 8 + 6], keys[s * 8 + 7], (unsigned)e);
      float m = floorf(u + 0.1f);
      float co = c2[e], so = s2s[e];
      float cn = fmaf(gatef(gf), co, gatef(gi) * tanhf(gc));
      float cnew = (m > 0.5f) ? co : cn;
      float sn = gatef(go) * tanhf(cnew);
      c2[e] = cnew;
      s2n[e] = (m > 0.5f) ? so : sn;
    }
    gbar(flags, genarr, ++gcount);
  }
}

// ---------------------------------------------------------------------------
// k_frame: deferred frame/token projection. grid 250.
// ---------------------------------------------------------------------------
__global__ __launch_bounds__(256) void k_frame(const float* __restrict__ s2_all,
                                               const float* __restrict__ g_all,
                                               const float* __restrict__ Wf,
                                               const float* __restrict__ bf,
                                               const float* __restrict__ Wt,
                                               const float* __restrict__ bt,
                                               float* __restrict__ out_frame,
                                               float* __restrict__ out_tok) {
  int s = blockIdx.x, t = threadIdx.x;
  __shared__ __align__(16) float xs[32 * 516];
  int b = t >> 3, ci = t & 7;
  int tb = t >> 1, tr = t & 1;
  float4 acc[5];
#pragma unroll
  for (int r = 0; r < 5; ++r) acc[r] = make_float4(0, 0, 0, 0);
  float tok = 0.f;
  for (int ch = 0; ch < 3; ++ch) {
    for (int i = 0; i < 64; ++i) {
      int idx = t + 256 * i;
      int rb = idx >> 9, kk = idx & 511;
      float vsrc = (ch < 2) ? s2_all[(size_t)(s + 1) * 32768 + rb * 1024 + ch * 512 + kk]
                            : g_all[(size_t)s * 16384 + rb * 512 + kk];
      xs[rb * 516 + kk] = vsrc;
    }
    __syncthreads();
    const float4* xv = (const float4*)xs;
    for (int k4 = 0; k4 < 128; ++k4) {
      float4 x4 = xv[b * 129 + k4];
      int kglob = ch * 512 + k4 * 4;
#pragma unroll
      for (int rep = 0; rep < 5; ++rep) {
        int c4 = ci * 4 + rep * 32;
        const float* wrow = Wf + (size_t)kglob * 160 + c4;
        float4 w0 = *(const float4*)(wrow);
        float4 w1 = *(const float4*)(wrow + 160);
        float4 w2 = *(const float4*)(wrow + 320);
        float4 w3 = *(const float4*)(wrow + 480);
        FMA4(acc[rep], x4.x, w0); FMA4(acc[rep], x4.y, w1);
        FMA4(acc[rep], x4.z, w2); FMA4(acc[rep], x4.w, w3);
      }
      if (t < 64) {
        float4 xt = xv[tb * 129 + k4];
        tok = fmaf(xt.x, Wt[(size_t)(kglob + 0) * 2 + tr], tok);
        tok = fmaf(xt.y, Wt[(size_t)(kglob + 1) * 2 + tr], tok);
        tok = fmaf(xt.z, Wt[(size_t)(kglob + 2) * 2 + tr], tok);
        tok = fmaf(xt.w, Wt[(size_t)(kglob + 3) * 2 + tr], tok);
      }
    }
    __syncthreads();
  }
#pragma unroll
  for (int rep = 0; rep < 5; ++rep) {
    float vals[4] = {acc[rep].x, acc[rep].y, acc[rep].z, acc[rep].w};
#pragma unroll
    for (int jj = 0; jj < 4; ++jj) {
      int cc = ci * 4 + rep * 32 + jj;
      float val = vals[jj] + bf[cc];
      int row = 2 * s + (cc >= 80 ? 1 : 0);
      int col = cc - (cc >= 80 ? 80 : 0);
      out_frame[(size_t)b * 40000 + (size_t)row * 80 + col] = val;
    }
  }
  if (t < 64) out_tok[(size_t)tb * 500 + 2 * s + tr] = tok + bt[tr];
}

// ---------------------------------------------------------------------------
extern "C" void kernel_launch(void* const* d_in, const int* in_sizes, int n_in,
                              void* d_out_v, int out_size, void* d_ws, size_t ws_size,
                              hipStream_t stream) {
  (void)in_sizes; (void)n_in; (void)out_size; (void)ws_size;
  const float* mel      = (const float*)d_in[0];
  const float* e_out    = (const float*)d_in[1];
  const float* conv_w   = (const float*)d_in[2];
  const float* Wcp      = (const float*)d_in[3];
  const float* Wenc     = (const float*)d_in[4];
  const float* benc     = (const float*)d_in[5];
  const float* Wdec     = (const float*)d_in[6];
  const float* Wself    = (const float*)d_in[7];
  const float* Wp1      = (const float*)d_in[8];
  const float* bp1      = (const float*)d_in[9];
  const float* Wp2      = (const float*)d_in[10];
  const float* bp2      = (const float*)d_in[11];
  const float* Wys      = (const float*)d_in[12];
  const float* Wss      = (const float*)d_in[13];
  const float* Wgs      = (const float*)d_in[14];
  const float* bgs      = (const float*)d_in[15];
  const float* Wis      = (const float*)d_in[16];
  const float* Wss2     = (const float*)d_in[17];
  const float* bss2     = (const float*)d_in[18];
  const float* Wf       = (const float*)d_in[19];
  const float* bf       = (const float*)d_in[20];
  const float* Wt       = (const float*)d_in[21];
  const float* bt       = (const float*)d_in[22];
  float* ws  = (float*)d_ws;
  float* out = (float*)d_out_v;
  const unsigned* keys = (const unsigned*)(ws + OFF_KEYS);

  hipLaunchKernelGGL(k_init, dim3(1024), dim3(256), 0, stream, ws, out, conv_w, Wcp);
  hipLaunchKernelGGL(k_encproj, dim3(200), dim3(256), 0, stream, e_out, Wenc, benc, ws + OFF_ENCPROJ);
  hipLaunchKernelGGL(k_prenet, dim3(250), dim3(256), 0, stream, mel, Wp1, bp1, Wp2, bp2, keys, ws + OFF_PRE2);

  KP kp;
  kp.e_out = e_out; kp.Wdec = Wdec; kp.Wself = Wself;
  kp.Wys = Wys; kp.Wss = Wss; kp.Wgs = Wgs; kp.bgs = bgs;
  kp.Wis = Wis; kp.Wss2 = Wss2; kp.bss2 = bss2;
  kp.ws = ws; kp.out = out;
  hipLaunchKernelGGL(k_loop, dim3(GRID), dim3(256), 0, stream, kp);

  hipLaunchKernelGGL(k_frame, dim3(250), dim3(256), 0, stream,
                     ws + OFF_S2, ws + OFF_G, Wf, bf, Wt, bt, out, out + OUT_TOK);
}